// Round 6
// baseline (311.092 us; speedup 1.0000x reference)
//
#include <hip/hip_runtime.h>

#define NUM_HEADS 16
#define HEAD_DIM  64
#define EMB       1024
#define SEQ       2048
#define BATCH     4
#define MROWS     (BATCH * SEQ)          // 8192
#define QKV_ELEMS (MROWS * EMB)          // 8388608

typedef __attribute__((ext_vector_type(4)))  float  floatx4;
typedef __attribute__((ext_vector_type(16))) float  floatx16;
typedef __attribute__((ext_vector_type(8)))  __bf16 bf16x8;

__device__ __forceinline__ unsigned short f2bf(float f) {
    unsigned int u = __float_as_uint(f);
    u += 0x7fffu + ((u >> 16) & 1u);
    return (unsigned short)(u >> 16);
}

__device__ __forceinline__ ushort4 pk4(float4 v) {
    return make_ushort4(f2bf(v.x), f2bf(v.y), f2bf(v.z), f2bf(v.w));
}

// pack 4 fp32 -> 4 bf16 (round-half-up) in 2 uints via v_perm_b32
__device__ __forceinline__ uint2 packbf4(float a0, float a1, float a2, float a3) {
    unsigned r0 = __float_as_uint(a0) + 0x8000u;
    unsigned r1 = __float_as_uint(a1) + 0x8000u;
    unsigned r2 = __float_as_uint(a2) + 0x8000u;
    unsigned r3 = __float_as_uint(a3) + 0x8000u;
    uint2 r;
    r.x = __builtin_amdgcn_perm(r1, r0, 0x07060302u);   // {bf(a1), bf(a0)}
    r.y = __builtin_amdgcn_perm(r3, r2, 0x07060302u);   // {bf(a3), bf(a2)}
    return r;
}

__device__ __forceinline__ bf16x8 mk8(uint2 lo, uint2 hi) {
    union { uint4 u; bf16x8 b; } cvt;
    cvt.u = make_uint4(lo.x, lo.y, hi.x, hi.y);
    return cvt.b;
}

#define MFMA16(a, b, c) __builtin_amdgcn_mfma_f32_16x16x32_bf16((a), (b), (c), 0, 0, 0)
#define MFMA32(a, b, c) __builtin_amdgcn_mfma_f32_32x32x16_bf16((a), (b), (c), 0, 0, 0)

// async global->LDS, 16B per lane; LDS dest = wave-uniform base + lane*16
__device__ __forceinline__ void async16(const unsigned short* g, unsigned short* l) {
    __builtin_amdgcn_global_load_lds((const __attribute__((address_space(1))) void*)g,
                                     (__attribute__((address_space(3))) void*)l,
                                     16, 0, 0);
}

// q scale folded with log2(e): 0.125 * 1.4426950408889634
#define QSCALE 0.18033688011112042f

// ---------------------------------------------------------------------------
// Kernel 0: fp32 -> bf16 conversion of x, qkv_w, fc_w (memory-bound pre-pass)
// ---------------------------------------------------------------------------
#define XV4  2097152   // 8388608/4
#define QWV4 786432    // 3145728/4
#define FWV4 262144    // 1048576/4

__global__ __launch_bounds__(256)
void convert_kernel(const float* __restrict__ x, const float* __restrict__ qw,
                    const float* __restrict__ fw,
                    unsigned short* __restrict__ xb, unsigned short* __restrict__ qwb,
                    unsigned short* __restrict__ fwb)
{
    const size_t i = (size_t)blockIdx.x * 256 + threadIdx.x;   // float4 units
    const float* src; unsigned short* dst; size_t off;
    if (i < XV4)              { src = x;  dst = xb;  off = i; }
    else if (i < XV4 + QWV4)  { src = qw; dst = qwb; off = i - XV4; }
    else                      { src = fw; dst = fwb; off = i - (XV4 + QWV4); }
    float4 v = ((const float4*)src)[off];
    ((ushort4*)dst)[off] = pk4(v);
}

// ---------------------------------------------------------------------------
// Kernel 1: qkv = xb @ qkv_w^T + qkv_b  (all-bf16 m97-style GEMM)
//           -> Q (scaled, [b,h,n,d]), K ([b,h,n,d]), V^T ([b,h,d,n]); bf16.
// ---------------------------------------------------------------------------
__global__ __launch_bounds__(256, 3)
void qkv_kernel(const unsigned short* __restrict__ X, const unsigned short* __restrict__ W,
                const float* __restrict__ BIAS,
                unsigned short* __restrict__ qb, unsigned short* __restrict__ kb,
                unsigned short* __restrict__ vtb)
{
    __shared__ unsigned short As[128 * 32];   // contiguous (global_load_lds layout)
    __shared__ unsigned short Bs[128 * 32];

    const int t    = threadIdx.x;
    const int n0   = blockIdx.x * 128;
    const int m0   = blockIdx.y * 128;
    const int wave = t >> 6, lane = t & 63;
    const int wm   = wave & 1, wn = wave >> 1;
    const int l15  = lane & 15, quad = lane >> 4;

    const int srow = wave * 32 + (lane >> 2);
    const int scol = (lane & 3) * 8;
    const unsigned short* gA = X + (size_t)(m0 + srow) * EMB + scol;
    const unsigned short* gB = W + (size_t)(n0 + srow) * EMB + scol;
    unsigned short* lA = &As[srow * 32 + scol];
    unsigned short* lB = &Bs[srow * 32 + scol];

    const floatx4 zero4 = {0.f, 0.f, 0.f, 0.f};
    floatx4 acc[4][4];
    #pragma unroll
    for (int i = 0; i < 4; ++i)
        #pragma unroll
        for (int j = 0; j < 4; ++j) acc[i][j] = zero4;

    for (int k0 = 0; k0 < EMB; k0 += 32) {
        __syncthreads();
        async16(gA + k0,                     lA);
        async16(gA + k0 + (size_t)16 * EMB,  lA + 16 * 32);
        async16(gB + k0,                     lB);
        async16(gB + k0 + (size_t)16 * EMB,  lB + 16 * 32);
        __syncthreads();

        bf16x8 af[4], bfv[4];
        #pragma unroll
        for (int i = 0; i < 4; ++i) {
            af[i]  = *(const bf16x8*)&As[(wm * 64 + i * 16 + l15) * 32 + quad * 8];
            bfv[i] = *(const bf16x8*)&Bs[(wn * 64 + i * 16 + l15) * 32 + quad * 8];
        }
        #pragma unroll
        for (int mi = 0; mi < 4; ++mi)
            #pragma unroll
            for (int ni = 0; ni < 4; ++ni)
                acc[mi][ni] = MFMA16(af[mi], bfv[ni], acc[mi][ni]);
    }

    const int bb = m0 >> 11;   // batch (tiles never straddle a batch)
    #pragma unroll
    for (int ni = 0; ni < 4; ++ni) {
        const int gc     = n0 + wn * 64 + ni * 16 + l15;
        const float bias = BIAS[gc];
        const int which  = gc >> 10;          // 0=q 1=k 2=v (uniform per block)
        const int rem    = gc & 1023;
        const int hh     = rem >> 6;
        const int dd     = rem & 63;
        #pragma unroll
        for (int mi = 0; mi < 4; ++mi) {
            const int nseq0 = (m0 & 2047) + wm * 64 + mi * 16 + quad * 4;
            floatx4 v = acc[mi][ni];
            if (which == 2) {
                ushort4 pk;
                pk.x = f2bf(v[0] + bias); pk.y = f2bf(v[1] + bias);
                pk.z = f2bf(v[2] + bias); pk.w = f2bf(v[3] + bias);
                *(ushort4*)&vtb[((size_t)(bb * NUM_HEADS + hh) * HEAD_DIM + dd) * SEQ + nseq0] = pk;
            } else {
                unsigned short* dst = which ? kb : qb;
                const float sc = which ? 1.0f : QSCALE;
                #pragma unroll
                for (int r = 0; r < 4; ++r)
                    dst[((size_t)(bb * NUM_HEADS + hh) * SEQ + (nseq0 + r)) * HEAD_DIM + dd] =
                        f2bf((v[r] + bias) * sc);
            }
        }
    }
}

// ---------------------------------------------------------------------------
// Kernel 2: flash attention on mfma_32x32x16. P never touches LDS: the S^T
// C-layout (col=l&31, row=(r&3)+8(r>>2)+4*(l>>5)) converts to the PV A-layout
// (m=l&31, k=(l>>5)*8+j) by exchanging half the packed regs between lane
// halves via __shfl_xor(32). Fixed-max softmax; denominator via ones-MFMA.
// LDS: K[0,8192) two [128][32] halves | V[8192,16384) four [64][32] quarters
//      Q[16384,24576) two [128][32] halves.  48 KB -> 3 blocks/CU if VGPR<=128.
// ---------------------------------------------------------------------------
__global__ __launch_bounds__(256, 2)
void attn_kernel(const unsigned short* __restrict__ qb, const unsigned short* __restrict__ kb,
                 const unsigned short* __restrict__ vtb, unsigned short* __restrict__ attnb)
{
    __shared__ unsigned short smem[24576];   // 48 KB

    const int t    = threadIdx.x;
    const int bh   = blockIdx.x;
    const int q0   = blockIdx.y * 128;
    const int b    = bh >> 4, hh = bh & 15;
    const int wave = t >> 6, lane = t & 63;
    const int l31  = lane & 31, hl = lane >> 5;
    const int srow = lane >> 2;              // 0..15
    const int scol = (lane & 3) * 8;

    const unsigned short* qp = qb  + (size_t)bh * SEQ * HEAD_DIM;
    const unsigned short* kp = kb  + (size_t)bh * SEQ * HEAD_DIM;
    const unsigned short* vp = vtb + (size_t)bh * HEAD_DIM * SEQ;

    // ---- stage Q (async DMA) into [16384,24576) as two [128][32] halves ----
    {
        const int r0 = wave * 32 + srow;
        async16(qp + (size_t)(q0 + r0) * 64 + scol,           &smem[16384 + r0 * 32 + scol]);
        async16(qp + (size_t)(q0 + r0 + 16) * 64 + scol,      &smem[16384 + (r0 + 16) * 32 + scol]);
        async16(qp + (size_t)(q0 + r0) * 64 + 32 + scol,      &smem[20480 + r0 * 32 + scol]);
        async16(qp + (size_t)(q0 + r0 + 16) * 64 + 32 + scol, &smem[20480 + (r0 + 16) * 32 + scol]);
    }
    __syncthreads();
    // Q B-frags (32x32x16): n=q=wave*32+l31, k=d=ks*16+hl*8+j — loop-invariant
    bf16x8 qf[4];
    #pragma unroll
    for (int ks = 0; ks < 4; ++ks)
        qf[ks] = *(const bf16x8*)&smem[16384 + (ks >> 1) * 4096 +
                 (wave * 32 + l31) * 32 + (ks & 1) * 16 + hl * 8];

    bf16x8 ones;
    #pragma unroll
    for (int i = 0; i < 8; ++i) ones[i] = (__bf16)1.0f;

    floatx16 o[2], o_sum;
    #pragma unroll
    for (int i = 0; i < 16; ++i) { o[0][i] = 0.f; o[1][i] = 0.f; o_sum[i] = 0.f; }

    for (int kv0 = 0; kv0 < SEQ; kv0 += 128) {
        __syncthreads();   // previous iteration's K/V reads done
        {
            const int kr = wave * 32 + srow;
            async16(kp + (size_t)(kv0 + kr) * 64 + scol,           &smem[kr * 32 + scol]);
            async16(kp + (size_t)(kv0 + kr + 16) * 64 + scol,      &smem[(kr + 16) * 32 + scol]);
            async16(kp + (size_t)(kv0 + kr) * 64 + 32 + scol,      &smem[4096 + kr * 32 + scol]);
            async16(kp + (size_t)(kv0 + kr + 16) * 64 + 32 + scol, &smem[4096 + (kr + 16) * 32 + scol]);
            const int vd = wave * 16 + srow;   // 0..63
            #pragma unroll
            for (int kk = 0; kk < 4; ++kk)
                async16(vp + (size_t)vd * SEQ + kv0 + kk * 32 + scol,
                        &smem[8192 + kk * 2048 + vd * 32 + scol]);
        }
        __syncthreads();

        #pragma unroll
        for (int tt = 0; tt < 4; ++tt) {        // 32-kv tiles
            // S^T tile: A=K (m=kv=tt*32+l31, k=d), B=Q
            floatx16 st;
            #pragma unroll
            for (int i = 0; i < 16; ++i) st[i] = 0.f;
            #pragma unroll
            for (int ks = 0; ks < 4; ++ks) {
                bf16x8 kf = *(const bf16x8*)&smem[(ks >> 1) * 4096 +
                            (tt * 32 + l31) * 32 + (ks & 1) * 16 + hl * 8];
                st = MFMA32(kf, qf[ks], st);
            }
            // exp2 + pack: pk[g] holds kv {8g+4hl .. 8g+4hl+3} for q=l31
            uint2 pk0 = packbf4(exp2f(st[0]),  exp2f(st[1]),  exp2f(st[2]),  exp2f(st[3]));
            uint2 pk1 = packbf4(exp2f(st[4]),  exp2f(st[5]),  exp2f(st[6]),  exp2f(st[7]));
            uint2 pk2 = packbf4(exp2f(st[8]),  exp2f(st[9]),  exp2f(st[10]), exp2f(st[11]));
            uint2 pk3 = packbf4(exp2f(st[12]), exp2f(st[13]), exp2f(st[14]), exp2f(st[15]));

            // C->A layout fix: exchange across lane halves (shfl_xor 32)
            uint2 xa = hl ? pk0 : pk1;
            xa.x = __shfl_xor(xa.x, 32); xa.y = __shfl_xor(xa.y, 32);
            bf16x8 pfA = hl ? mk8(xa, pk1) : mk8(pk0, xa);   // kv blk tt*2+0
            uint2 xb2 = hl ? pk2 : pk3;
            xb2.x = __shfl_xor(xb2.x, 32); xb2.y = __shfl_xor(xb2.y, 32);
            bf16x8 pfB = hl ? mk8(xb2, pk3) : mk8(pk2, xb2); // kv blk tt*2+1

            // PV: O[q][d] += P @ V ; o_sum += P @ ones
            #pragma unroll
            for (int s = 0; s < 2; ++s) {
                const bf16x8 pf   = s ? pfB : pfA;
                const int kvblk   = tt * 2 + s;              // 16-kv block 0..7
                const int qoff    = 8192 + (kvblk >> 1) * 2048 + (kvblk & 1) * 16 + hl * 8;
                #pragma unroll
                for (int dt = 0; dt < 2; ++dt) {
                    bf16x8 vf = *(const bf16x8*)&smem[qoff + (dt * 32 + l31) * 32];
                    o[dt] = MFMA32(pf, vf, o[dt]);
                }
                o_sum = MFMA32(pf, ones, o_sum);
            }
        }
    }

    // epilogue: O/l -> attn buffer [b, n, hh*64+d] bf16 (denominator in-lane:
    // o and o_sum share the C row mapping q=(e)+8g+4hl, col d=dt*32+l31)
    #pragma unroll
    for (int g = 0; g < 4; ++g)
        #pragma unroll
        for (int e = 0; e < 4; ++e) {
            const float inv  = 1.0f / o_sum[g * 4 + e];
            const int  qrow  = q0 + wave * 32 + e + g * 8 + hl * 4;
            #pragma unroll
            for (int dt = 0; dt < 2; ++dt)
                attnb[(size_t)(b * SEQ + qrow) * EMB + hh * HEAD_DIM + dt * 32 + l31] =
                    f2bf(o[dt][g * 4 + e] * inv);
        }
}

// ---------------------------------------------------------------------------
// Kernel 3: out = attn @ fc_w^T + fc_b  (all-bf16 m97-style GEMM, fp32 out)
// ---------------------------------------------------------------------------
__global__ __launch_bounds__(256, 3)
void proj_kernel(const unsigned short* __restrict__ A, const unsigned short* __restrict__ W,
                 const float* __restrict__ BIAS, float* __restrict__ out)
{
    __shared__ unsigned short As[128 * 32];
    __shared__ unsigned short Bs[128 * 32];

    const int t    = threadIdx.x;
    const int n0   = blockIdx.x * 128;
    const int m0   = blockIdx.y * 128;
    const int wave = t >> 6, lane = t & 63;
    const int wm   = wave & 1, wn = wave >> 1;
    const int l15  = lane & 15, quad = lane >> 4;

    const int srow = wave * 32 + (lane >> 2);
    const int scol = (lane & 3) * 8;
    const unsigned short* gA = A + (size_t)(m0 + srow) * EMB + scol;
    const unsigned short* gB = W + (size_t)(n0 + srow) * EMB + scol;
    unsigned short* lA = &As[srow * 32 + scol];
    unsigned short* lB = &Bs[srow * 32 + scol];

    const floatx4 zero4 = {0.f, 0.f, 0.f, 0.f};
    floatx4 acc[4][4];
    #pragma unroll
    for (int i = 0; i < 4; ++i)
        #pragma unroll
        for (int j = 0; j < 4; ++j) acc[i][j] = zero4;

    for (int k0 = 0; k0 < EMB; k0 += 32) {
        __syncthreads();
        async16(gA + k0,                     lA);
        async16(gA + k0 + (size_t)16 * EMB,  lA + 16 * 32);
        async16(gB + k0,                     lB);
        async16(gB + k0 + (size_t)16 * EMB,  lB + 16 * 32);
        __syncthreads();

        bf16x8 af[4], bfv[4];
        #pragma unroll
        for (int i = 0; i < 4; ++i) {
            af[i]  = *(const bf16x8*)&As[(wm * 64 + i * 16 + l15) * 32 + quad * 8];
            bfv[i] = *(const bf16x8*)&Bs[(wn * 64 + i * 16 + l15) * 32 + quad * 8];
        }
        #pragma unroll
        for (int mi = 0; mi < 4; ++mi)
            #pragma unroll
            for (int ni = 0; ni < 4; ++ni)
                acc[mi][ni] = MFMA16(af[mi], bfv[ni], acc[mi][ni]);
    }

    #pragma unroll
    for (int ni = 0; ni < 4; ++ni) {
        const int gc     = n0 + wn * 64 + ni * 16 + l15;
        const float bias = BIAS[gc];
        #pragma unroll
        for (int mi = 0; mi < 4; ++mi) {
            const int gm = m0 + wm * 64 + mi * 16 + quad * 4;
            #pragma unroll
            for (int r = 0; r < 4; ++r)
                out[(size_t)(gm + r) * EMB + gc] = acc[mi][ni][r] + bias;
        }
    }
}

// ---------------------------------------------------------------------------
extern "C" void kernel_launch(void* const* d_in, const int* in_sizes, int n_in,
                              void* d_out, int out_size, void* d_ws, size_t ws_size,
                              hipStream_t stream) {
    (void)in_sizes; (void)n_in; (void)out_size; (void)ws_size;
    const float* x     = (const float*)d_in[0];
    const float* qkv_w = (const float*)d_in[1];
    const float* qkv_b = (const float*)d_in[2];
    const float* fc_w  = (const float*)d_in[3];
    const float* fc_b  = (const float*)d_in[4];
    float* out = (float*)d_out;

    unsigned short* xb    = (unsigned short*)d_ws;        // 8.4M  (also attnb)
    unsigned short* attnb = xb;
    unsigned short* qbuf  = xb    + QKV_ELEMS;
    unsigned short* kbuf  = qbuf  + QKV_ELEMS;
    unsigned short* vtbuf = kbuf  + QKV_ELEMS;
    unsigned short* qwb   = vtbuf + QKV_ELEMS;            // 3.1M
    unsigned short* fwb   = qwb   + 3 * EMB * EMB;        // 1.0M

    convert_kernel<<<dim3((XV4 + QWV4 + FWV4) / 256), 256, 0, stream>>>(
        x, qkv_w, fc_w, xb, qwb, fwb);
    qkv_kernel<<<dim3(24, 64), 256, 0, stream>>>(xb, qwb, qkv_b, qbuf, kbuf, vtbuf);
    attn_kernel<<<dim3(64, 16), 256, 0, stream>>>(qbuf, kbuf, vtbuf, attnb);
    proj_kernel<<<dim3(8, 64), 256, 0, stream>>>(attnb, fwb, fc_b, out);
}

// Round 7
// 306.816 us; speedup vs baseline: 1.0139x; 1.0139x over previous
//
#include <hip/hip_runtime.h>

#define NUM_HEADS 16
#define HEAD_DIM  64
#define EMB       1024
#define SEQ       2048
#define BATCH     4
#define MROWS     (BATCH * SEQ)          // 8192
#define QKV_ELEMS (MROWS * EMB)          // 8388608

typedef __attribute__((ext_vector_type(4)))  float  floatx4;
typedef __attribute__((ext_vector_type(16))) float  floatx16;
typedef __attribute__((ext_vector_type(8)))  __bf16 bf16x8;

__device__ __forceinline__ unsigned short f2bf(float f) {
    unsigned int u = __float_as_uint(f);
    u += 0x7fffu + ((u >> 16) & 1u);
    return (unsigned short)(u >> 16);
}

__device__ __forceinline__ ushort4 pk4(float4 v) {
    return make_ushort4(f2bf(v.x), f2bf(v.y), f2bf(v.z), f2bf(v.w));
}

// pack 4 fp32 -> 4 bf16 (round-half-up) in 2 uints via v_perm_b32
__device__ __forceinline__ uint2 packbf4(float a0, float a1, float a2, float a3) {
    unsigned r0 = __float_as_uint(a0) + 0x8000u;
    unsigned r1 = __float_as_uint(a1) + 0x8000u;
    unsigned r2 = __float_as_uint(a2) + 0x8000u;
    unsigned r3 = __float_as_uint(a3) + 0x8000u;
    uint2 r;
    r.x = __builtin_amdgcn_perm(r1, r0, 0x07060302u);   // {bf(a1), bf(a0)}
    r.y = __builtin_amdgcn_perm(r3, r2, 0x07060302u);   // {bf(a3), bf(a2)}
    return r;
}

__device__ __forceinline__ bf16x8 mk8(uint2 lo, uint2 hi) {
    union { uint4 u; bf16x8 b; } cvt;
    cvt.u = make_uint4(lo.x, lo.y, hi.x, hi.y);
    return cvt.b;
}

#define MFMA16(a, b, c) __builtin_amdgcn_mfma_f32_16x16x32_bf16((a), (b), (c), 0, 0, 0)
#define MFMA32(a, b, c) __builtin_amdgcn_mfma_f32_32x32x16_bf16((a), (b), (c), 0, 0, 0)

// async global->LDS, 16B per lane; LDS dest = wave-uniform base + lane*16
__device__ __forceinline__ void async16(const unsigned short* g, unsigned short* l) {
    __builtin_amdgcn_global_load_lds((const __attribute__((address_space(1))) void*)g,
                                     (__attribute__((address_space(3))) void*)l,
                                     16, 0, 0);
}

// Bank-conflict-killing chunk rotation for [N][32] DMA tiles:
// row R's four 16B chunks are stored rotated by (R>>1)&3. Staging lane i
// (R = base + (i>>2), base % 8 == 0) therefore fetches LOGICAL chunk
// ((i&3) - ((i>>3)&3)) & 3; readers use phys chunk (C + ((R>>1)&3)) & 3.
// Result: a quarter-wave's 16 b128 reads hit all 8 bank groups twice (free).

// q scale folded with log2(e): 0.125 * 1.4426950408889634
#define QSCALE 0.18033688011112042f

// ---------------------------------------------------------------------------
// Kernel 0: fp32 -> bf16 conversion of x, qkv_w, fc_w (memory-bound pre-pass)
// ---------------------------------------------------------------------------
#define XV4  2097152   // 8388608/4
#define QWV4 786432    // 3145728/4
#define FWV4 262144    // 1048576/4

__global__ __launch_bounds__(256)
void convert_kernel(const float* __restrict__ x, const float* __restrict__ qw,
                    const float* __restrict__ fw,
                    unsigned short* __restrict__ xb, unsigned short* __restrict__ qwb,
                    unsigned short* __restrict__ fwb)
{
    const size_t i = (size_t)blockIdx.x * 256 + threadIdx.x;   // float4 units
    const float* src; unsigned short* dst; size_t off;
    if (i < XV4)              { src = x;  dst = xb;  off = i; }
    else if (i < XV4 + QWV4)  { src = qw; dst = qwb; off = i - XV4; }
    else                      { src = fw; dst = fwb; off = i - (XV4 + QWV4); }
    float4 v = ((const float4*)src)[off];
    ((ushort4*)dst)[off] = pk4(v);
}

// ---------------------------------------------------------------------------
// Kernel 1: qkv = xb @ qkv_w^T + qkv_b  (all-bf16 m97-style GEMM, rot-swizzled
//           LDS) -> Q (scaled,[b,h,n,d]), K ([b,h,n,d]), V^T ([b,h,d,n]); bf16
// ---------------------------------------------------------------------------
__global__ __launch_bounds__(256, 3)
void qkv_kernel(const unsigned short* __restrict__ X, const unsigned short* __restrict__ W,
                const float* __restrict__ BIAS,
                unsigned short* __restrict__ qb, unsigned short* __restrict__ kb,
                unsigned short* __restrict__ vtb)
{
    __shared__ unsigned short As[128 * 32];
    __shared__ unsigned short Bs[128 * 32];

    const int t    = threadIdx.x;
    const int n0   = blockIdx.x * 128;
    const int m0   = blockIdx.y * 128;
    const int wave = t >> 6, lane = t & 63;
    const int wm   = wave & 1, wn = wave >> 1;
    const int l15  = lane & 15, quad = lane >> 4;

    const int srow = wave * 32 + (lane >> 2);
    const int scol = (lane & 3) * 8;                              // phys chunk
    const int gcol = (((lane & 3) - ((lane >> 3) & 3)) & 3) * 8;  // logical chunk
    const unsigned short* gA = X + (size_t)(m0 + srow) * EMB + gcol;
    const unsigned short* gB = W + (size_t)(n0 + srow) * EMB + gcol;
    unsigned short* lA = &As[srow * 32 + scol];
    unsigned short* lB = &Bs[srow * 32 + scol];

    const int arot = (l15 >> 1) & 3;

    const floatx4 zero4 = {0.f, 0.f, 0.f, 0.f};
    floatx4 acc[4][4];
    #pragma unroll
    for (int i = 0; i < 4; ++i)
        #pragma unroll
        for (int j = 0; j < 4; ++j) acc[i][j] = zero4;

    for (int k0 = 0; k0 < EMB; k0 += 32) {
        __syncthreads();
        async16(gA + k0,                     lA);
        async16(gA + k0 + (size_t)16 * EMB,  lA + 16 * 32);
        async16(gB + k0,                     lB);
        async16(gB + k0 + (size_t)16 * EMB,  lB + 16 * 32);
        __syncthreads();

        bf16x8 af[4], bfv[4];
        #pragma unroll
        for (int i = 0; i < 4; ++i) {
            const int pc = ((quad + arot) & 3) * 8;
            af[i]  = *(const bf16x8*)&As[(wm * 64 + i * 16 + l15) * 32 + pc];
            bfv[i] = *(const bf16x8*)&Bs[(wn * 64 + i * 16 + l15) * 32 + pc];
        }
        #pragma unroll
        for (int mi = 0; mi < 4; ++mi)
            #pragma unroll
            for (int ni = 0; ni < 4; ++ni)
                acc[mi][ni] = MFMA16(af[mi], bfv[ni], acc[mi][ni]);
    }

    const int bb = m0 >> 11;   // batch (tiles never straddle a batch)
    #pragma unroll
    for (int ni = 0; ni < 4; ++ni) {
        const int gc     = n0 + wn * 64 + ni * 16 + l15;
        const float bias = BIAS[gc];
        const int which  = gc >> 10;          // 0=q 1=k 2=v (uniform per block)
        const int rem    = gc & 1023;
        const int hh     = rem >> 6;
        const int dd     = rem & 63;
        #pragma unroll
        for (int mi = 0; mi < 4; ++mi) {
            const int nseq0 = (m0 & 2047) + wm * 64 + mi * 16 + quad * 4;
            floatx4 v = acc[mi][ni];
            if (which == 2) {
                ushort4 pk;
                pk.x = f2bf(v[0] + bias); pk.y = f2bf(v[1] + bias);
                pk.z = f2bf(v[2] + bias); pk.w = f2bf(v[3] + bias);
                *(ushort4*)&vtb[((size_t)(bb * NUM_HEADS + hh) * HEAD_DIM + dd) * SEQ + nseq0] = pk;
            } else {
                unsigned short* dst = which ? kb : qb;
                const float sc = which ? 1.0f : QSCALE;
                #pragma unroll
                for (int r = 0; r < 4; ++r)
                    dst[((size_t)(bb * NUM_HEADS + hh) * SEQ + (nseq0 + r)) * HEAD_DIM + dd] =
                        f2bf((v[r] + bias) * sc);
            }
        }
    }
}

// ---------------------------------------------------------------------------
// Kernel 2: flash attention on mfma_32x32x16, register-resident P, rot-swizzled
// K/V/Q LDS tiles (conflict-free frag reads). Fixed-max softmax; denominator
// via ones-MFMA. LDS 48 KB.
// ---------------------------------------------------------------------------
__global__ __launch_bounds__(256, 2)
void attn_kernel(const unsigned short* __restrict__ qb, const unsigned short* __restrict__ kb,
                 const unsigned short* __restrict__ vtb, unsigned short* __restrict__ attnb)
{
    __shared__ unsigned short smem[24576];   // 48 KB

    const int t    = threadIdx.x;
    const int bh   = blockIdx.x;
    const int q0   = blockIdx.y * 128;
    const int b    = bh >> 4, hh = bh & 15;
    const int wave = t >> 6, lane = t & 63;
    const int l31  = lane & 31, hl = lane >> 5;
    const int srow = lane >> 2;              // 0..15
    const int scol = (lane & 3) * 8;                              // phys chunk
    const int gcol = (((lane & 3) - ((lane >> 3) & 3)) & 3) * 8;  // logical chunk
    const int rrot = (l31 >> 1) & 3;

    const unsigned short* qp = qb  + (size_t)bh * SEQ * HEAD_DIM;
    const unsigned short* kp = kb  + (size_t)bh * SEQ * HEAD_DIM;
    const unsigned short* vp = vtb + (size_t)bh * HEAD_DIM * SEQ;

    // ---- stage Q (async DMA) into [16384,24576) as two [128][32] halves ----
    {
        const int r0 = wave * 32 + srow;
        async16(qp + (size_t)(q0 + r0) * 64 + gcol,           &smem[16384 + r0 * 32 + scol]);
        async16(qp + (size_t)(q0 + r0 + 16) * 64 + gcol,      &smem[16384 + (r0 + 16) * 32 + scol]);
        async16(qp + (size_t)(q0 + r0) * 64 + 32 + gcol,      &smem[20480 + r0 * 32 + scol]);
        async16(qp + (size_t)(q0 + r0 + 16) * 64 + 32 + gcol, &smem[20480 + (r0 + 16) * 32 + scol]);
    }
    __syncthreads();
    // Q B-frags (32x32x16): n=q=wave*32+l31, k=d=ks*16+hl*8+j — loop-invariant
    bf16x8 qf[4];
    #pragma unroll
    for (int ks = 0; ks < 4; ++ks)
        qf[ks] = *(const bf16x8*)&smem[16384 + (ks >> 1) * 4096 +
                 (wave * 32 + l31) * 32 + ((((ks & 1) * 2 + hl) + rrot) & 3) * 8];

    bf16x8 ones;
    #pragma unroll
    for (int i = 0; i < 8; ++i) ones[i] = (__bf16)1.0f;

    floatx16 o[2], o_sum;
    #pragma unroll
    for (int i = 0; i < 16; ++i) { o[0][i] = 0.f; o[1][i] = 0.f; o_sum[i] = 0.f; }

    for (int kv0 = 0; kv0 < SEQ; kv0 += 128) {
        __syncthreads();   // previous iteration's K/V reads done
        {
            const int kr = wave * 32 + srow;
            async16(kp + (size_t)(kv0 + kr) * 64 + gcol,           &smem[kr * 32 + scol]);
            async16(kp + (size_t)(kv0 + kr + 16) * 64 + gcol,      &smem[(kr + 16) * 32 + scol]);
            async16(kp + (size_t)(kv0 + kr) * 64 + 32 + gcol,      &smem[4096 + kr * 32 + scol]);
            async16(kp + (size_t)(kv0 + kr + 16) * 64 + 32 + gcol, &smem[4096 + (kr + 16) * 32 + scol]);
            const int vd = wave * 16 + srow;   // 0..63
            #pragma unroll
            for (int kk = 0; kk < 4; ++kk)
                async16(vp + (size_t)vd * SEQ + kv0 + kk * 32 + gcol,
                        &smem[8192 + kk * 2048 + vd * 32 + scol]);
        }
        __syncthreads();

        #pragma unroll
        for (int tt = 0; tt < 4; ++tt) {        // 32-kv tiles
            // S^T tile: A=K (m=kv=tt*32+l31, k=d), B=Q
            floatx16 st;
            #pragma unroll
            for (int i = 0; i < 16; ++i) st[i] = 0.f;
            #pragma unroll
            for (int ks = 0; ks < 4; ++ks) {
                bf16x8 kf = *(const bf16x8*)&smem[(ks >> 1) * 4096 +
                            (tt * 32 + l31) * 32 + ((((ks & 1) * 2 + hl) + rrot) & 3) * 8];
                st = MFMA32(kf, qf[ks], st);
            }
            // exp2 + pack: pk[g] holds kv {8g+4hl .. 8g+4hl+3} for q=l31
            uint2 pk0 = packbf4(exp2f(st[0]),  exp2f(st[1]),  exp2f(st[2]),  exp2f(st[3]));
            uint2 pk1 = packbf4(exp2f(st[4]),  exp2f(st[5]),  exp2f(st[6]),  exp2f(st[7]));
            uint2 pk2 = packbf4(exp2f(st[8]),  exp2f(st[9]),  exp2f(st[10]), exp2f(st[11]));
            uint2 pk3 = packbf4(exp2f(st[12]), exp2f(st[13]), exp2f(st[14]), exp2f(st[15]));

            // C->A layout fix: exchange across lane halves (shfl_xor 32)
            uint2 xa = hl ? pk0 : pk1;
            xa.x = __shfl_xor(xa.x, 32); xa.y = __shfl_xor(xa.y, 32);
            bf16x8 pfA = hl ? mk8(xa, pk1) : mk8(pk0, xa);   // kv blk tt*2+0
            uint2 xb2 = hl ? pk2 : pk3;
            xb2.x = __shfl_xor(xb2.x, 32); xb2.y = __shfl_xor(xb2.y, 32);
            bf16x8 pfB = hl ? mk8(xb2, pk3) : mk8(pk2, xb2); // kv blk tt*2+1

            // PV: O[q][d] += P @ V ; o_sum += P @ ones
            #pragma unroll
            for (int s = 0; s < 2; ++s) {
                const bf16x8 pf = s ? pfB : pfA;
                const int kvblk = tt * 2 + s;                // 16-kv block 0..7
                const int vbase = 8192 + (kvblk >> 1) * 2048;
                const int vchun = ((((kvblk & 1) * 2 + hl) + rrot) & 3) * 8;
                #pragma unroll
                for (int dt = 0; dt < 2; ++dt) {
                    bf16x8 vf = *(const bf16x8*)&smem[vbase + (dt * 32 + l31) * 32 + vchun];
                    o[dt] = MFMA32(pf, vf, o[dt]);
                }
                o_sum = MFMA32(pf, ones, o_sum);
            }
        }
    }

    // epilogue: O/l -> attn buffer [b, n, hh*64+d] bf16 (denominator in-lane:
    // o and o_sum share the C row mapping q=(e)+8g+4hl, col d=dt*32+l31)
    #pragma unroll
    for (int g = 0; g < 4; ++g)
        #pragma unroll
        for (int e = 0; e < 4; ++e) {
            const float inv  = 1.0f / o_sum[g * 4 + e];
            const int  qrow  = q0 + wave * 32 + e + g * 8 + hl * 4;
            #pragma unroll
            for (int dt = 0; dt < 2; ++dt)
                attnb[(size_t)(b * SEQ + qrow) * EMB + hh * HEAD_DIM + dt * 32 + l31] =
                    f2bf(o[dt][g * 4 + e] * inv);
        }
}

// ---------------------------------------------------------------------------
// Kernel 3: out = attn @ fc_w^T + fc_b  (all-bf16 m97-style GEMM, rot-swizzled
//           LDS, fp32 out)
// ---------------------------------------------------------------------------
__global__ __launch_bounds__(256, 3)
void proj_kernel(const unsigned short* __restrict__ A, const unsigned short* __restrict__ W,
                 const float* __restrict__ BIAS, float* __restrict__ out)
{
    __shared__ unsigned short As[128 * 32];
    __shared__ unsigned short Bs[128 * 32];

    const int t    = threadIdx.x;
    const int n0   = blockIdx.x * 128;
    const int m0   = blockIdx.y * 128;
    const int wave = t >> 6, lane = t & 63;
    const int wm   = wave & 1, wn = wave >> 1;
    const int l15  = lane & 15, quad = lane >> 4;

    const int srow = wave * 32 + (lane >> 2);
    const int scol = (lane & 3) * 8;
    const int gcol = (((lane & 3) - ((lane >> 3) & 3)) & 3) * 8;
    const unsigned short* gA = A + (size_t)(m0 + srow) * EMB + gcol;
    const unsigned short* gB = W + (size_t)(n0 + srow) * EMB + gcol;
    unsigned short* lA = &As[srow * 32 + scol];
    unsigned short* lB = &Bs[srow * 32 + scol];

    const int arot = (l15 >> 1) & 3;

    const floatx4 zero4 = {0.f, 0.f, 0.f, 0.f};
    floatx4 acc[4][4];
    #pragma unroll
    for (int i = 0; i < 4; ++i)
        #pragma unroll
        for (int j = 0; j < 4; ++j) acc[i][j] = zero4;

    for (int k0 = 0; k0 < EMB; k0 += 32) {
        __syncthreads();
        async16(gA + k0,                     lA);
        async16(gA + k0 + (size_t)16 * EMB,  lA + 16 * 32);
        async16(gB + k0,                     lB);
        async16(gB + k0 + (size_t)16 * EMB,  lB + 16 * 32);
        __syncthreads();

        bf16x8 af[4], bfv[4];
        #pragma unroll
        for (int i = 0; i < 4; ++i) {
            const int pc = ((quad + arot) & 3) * 8;
            af[i]  = *(const bf16x8*)&As[(wm * 64 + i * 16 + l15) * 32 + pc];
            bfv[i] = *(const bf16x8*)&Bs[(wn * 64 + i * 16 + l15) * 32 + pc];
        }
        #pragma unroll
        for (int mi = 0; mi < 4; ++mi)
            #pragma unroll
            for (int ni = 0; ni < 4; ++ni)
                acc[mi][ni] = MFMA16(af[mi], bfv[ni], acc[mi][ni]);
    }

    #pragma unroll
    for (int ni = 0; ni < 4; ++ni) {
        const int gc     = n0 + wn * 64 + ni * 16 + l15;
        const float bias = BIAS[gc];
        #pragma unroll
        for (int mi = 0; mi < 4; ++mi) {
            const int gm = m0 + wm * 64 + mi * 16 + quad * 4;
            #pragma unroll
            for (int r = 0; r < 4; ++r)
                out[(size_t)(gm + r) * EMB + gc] = acc[mi][ni][r] + bias;
        }
    }
}

// ---------------------------------------------------------------------------
extern "C" void kernel_launch(void* const* d_in, const int* in_sizes, int n_in,
                              void* d_out, int out_size, void* d_ws, size_t ws_size,
                              hipStream_t stream) {
    (void)in_sizes; (void)n_in; (void)out_size; (void)ws_size;
    const float* x     = (const float*)d_in[0];
    const float* qkv_w = (const float*)d_in[1];
    const float* qkv_b = (const float*)d_in[2];
    const float* fc_w  = (const float*)d_in[3];
    const float* fc_b  = (const float*)d_in[4];
    float* out = (float*)d_out;

    unsigned short* xb    = (unsigned short*)d_ws;        // 8.4M  (also attnb)
    unsigned short* attnb = xb;
    unsigned short* qbuf  = xb    + QKV_ELEMS;
    unsigned short* kbuf  = qbuf  + QKV_ELEMS;
    unsigned short* vtbuf = kbuf  + QKV_ELEMS;
    unsigned short* qwb   = vtbuf + QKV_ELEMS;            // 3.1M
    unsigned short* fwb   = qwb   + 3 * EMB * EMB;        // 1.0M

    convert_kernel<<<dim3((XV4 + QWV4 + FWV4) / 256), 256, 0, stream>>>(
        x, qkv_w, fc_w, xb, qwb, fwb);
    qkv_kernel<<<dim3(24, 64), 256, 0, stream>>>(xb, qwb, qkv_b, qbuf, kbuf, vtbuf);
    attn_kernel<<<dim3(64, 16), 256, 0, stream>>>(qbuf, kbuf, vtbuf, attnb);
    proj_kernel<<<dim3(8, 64), 256, 0, stream>>>(attnb, fwb, fc_b, out);
}

// Round 8
// 272.091 us; speedup vs baseline: 1.1433x; 1.1276x over previous
//
#include <hip/hip_runtime.h>

#define NUM_HEADS 16
#define HEAD_DIM  64
#define EMB       1024
#define SEQ       2048
#define BATCH     4
#define MROWS     (BATCH * SEQ)          // 8192
#define QKV_ELEMS (MROWS * EMB)          // 8388608

typedef __attribute__((ext_vector_type(4)))  float  floatx4;
typedef __attribute__((ext_vector_type(16))) float  floatx16;
typedef __attribute__((ext_vector_type(8)))  __bf16 bf16x8;

__device__ __forceinline__ unsigned short f2bf(float f) {
    unsigned int u = __float_as_uint(f);
    u += 0x7fffu + ((u >> 16) & 1u);
    return (unsigned short)(u >> 16);
}

__device__ __forceinline__ ushort4 pk4(float4 v) {
    return make_ushort4(f2bf(v.x), f2bf(v.y), f2bf(v.z), f2bf(v.w));
}

// pack 4 fp32 -> 4 bf16 (TRUNCATING) in 2 uints via v_perm_b32.
// P feeds both numerator (P@V) and denominator (P@ones) from the same packed
// values, so the one-sided truncation bias largely cancels in O/l.
__device__ __forceinline__ uint2 packbf4t(float a0, float a1, float a2, float a3) {
    uint2 r;
    r.x = __builtin_amdgcn_perm(__float_as_uint(a1), __float_as_uint(a0), 0x07060302u);
    r.y = __builtin_amdgcn_perm(__float_as_uint(a3), __float_as_uint(a2), 0x07060302u);
    return r;
}

__device__ __forceinline__ bf16x8 mk8(uint2 lo, uint2 hi) {
    union { uint4 u; bf16x8 b; } cvt;
    cvt.u = make_uint4(lo.x, lo.y, hi.x, hi.y);
    return cvt.b;
}

#define MFMA16(a, b, c) __builtin_amdgcn_mfma_f32_16x16x32_bf16((a), (b), (c), 0, 0, 0)
#define MFMA32(a, b, c) __builtin_amdgcn_mfma_f32_32x32x16_bf16((a), (b), (c), 0, 0, 0)
#define EXP2(x) __builtin_amdgcn_exp2f(x)

// async global->LDS, 16B per lane; LDS dest = wave-uniform base + lane*16
__device__ __forceinline__ void async16(const unsigned short* g, unsigned short* l) {
    __builtin_amdgcn_global_load_lds((const __attribute__((address_space(1))) void*)g,
                                     (__attribute__((address_space(3))) void*)l,
                                     16, 0, 0);
}

// Bank-conflict-killing chunk rotation for [N][32] DMA tiles:
// row R's four 16B chunks are stored rotated by (R>>1)&3. Staging lane i
// (R = base + (i>>2), base % 8 == 0) fetches LOGICAL chunk
// ((i&3) - ((i>>3)&3)) & 3; readers use phys chunk (C + ((R>>1)&3)) & 3.

// q scale folded with log2(e): 0.125 * 1.4426950408889634
#define QSCALE 0.18033688011112042f

// ---------------------------------------------------------------------------
// Kernel 0: fp32 -> bf16 conversion of x, qkv_w, fc_w (memory-bound pre-pass)
// ---------------------------------------------------------------------------
#define XV4  2097152   // 8388608/4
#define QWV4 786432    // 3145728/4
#define FWV4 262144    // 1048576/4

__global__ __launch_bounds__(256)
void convert_kernel(const float* __restrict__ x, const float* __restrict__ qw,
                    const float* __restrict__ fw,
                    unsigned short* __restrict__ xb, unsigned short* __restrict__ qwb,
                    unsigned short* __restrict__ fwb)
{
    const size_t i = (size_t)blockIdx.x * 256 + threadIdx.x;   // float4 units
    const float* src; unsigned short* dst; size_t off;
    if (i < XV4)              { src = x;  dst = xb;  off = i; }
    else if (i < XV4 + QWV4)  { src = qw; dst = qwb; off = i - XV4; }
    else                      { src = fw; dst = fwb; off = i - (XV4 + QWV4); }
    float4 v = ((const float4*)src)[off];
    ((ushort4*)dst)[off] = pk4(v);
}

// ---------------------------------------------------------------------------
// Kernel 1: qkv = xb @ qkv_w^T + qkv_b  (all-bf16 m97-style GEMM, rot-swizzled
//           LDS) -> Q (scaled,[b,h,n,d]), K ([b,h,n,d]), V^T ([b,h,d,n]); bf16
// ---------------------------------------------------------------------------
__global__ __launch_bounds__(256, 3)
void qkv_kernel(const unsigned short* __restrict__ X, const unsigned short* __restrict__ W,
                const float* __restrict__ BIAS,
                unsigned short* __restrict__ qb, unsigned short* __restrict__ kb,
                unsigned short* __restrict__ vtb)
{
    __shared__ unsigned short As[128 * 32];
    __shared__ unsigned short Bs[128 * 32];

    const int t    = threadIdx.x;
    const int n0   = blockIdx.x * 128;
    const int m0   = blockIdx.y * 128;
    const int wave = t >> 6, lane = t & 63;
    const int wm   = wave & 1, wn = wave >> 1;
    const int l15  = lane & 15, quad = lane >> 4;

    const int srow = wave * 32 + (lane >> 2);
    const int scol = (lane & 3) * 8;                              // phys chunk
    const int gcol = (((lane & 3) - ((lane >> 3) & 3)) & 3) * 8;  // logical chunk
    const unsigned short* gA = X + (size_t)(m0 + srow) * EMB + gcol;
    const unsigned short* gB = W + (size_t)(n0 + srow) * EMB + gcol;
    unsigned short* lA = &As[srow * 32 + scol];
    unsigned short* lB = &Bs[srow * 32 + scol];

    const int arot = (l15 >> 1) & 3;

    const floatx4 zero4 = {0.f, 0.f, 0.f, 0.f};
    floatx4 acc[4][4];
    #pragma unroll
    for (int i = 0; i < 4; ++i)
        #pragma unroll
        for (int j = 0; j < 4; ++j) acc[i][j] = zero4;

    for (int k0 = 0; k0 < EMB; k0 += 32) {
        __syncthreads();
        async16(gA + k0,                     lA);
        async16(gA + k0 + (size_t)16 * EMB,  lA + 16 * 32);
        async16(gB + k0,                     lB);
        async16(gB + k0 + (size_t)16 * EMB,  lB + 16 * 32);
        __syncthreads();

        bf16x8 af[4], bfv[4];
        #pragma unroll
        for (int i = 0; i < 4; ++i) {
            const int pc = ((quad + arot) & 3) * 8;
            af[i]  = *(const bf16x8*)&As[(wm * 64 + i * 16 + l15) * 32 + pc];
            bfv[i] = *(const bf16x8*)&Bs[(wn * 64 + i * 16 + l15) * 32 + pc];
        }
        #pragma unroll
        for (int mi = 0; mi < 4; ++mi)
            #pragma unroll
            for (int ni = 0; ni < 4; ++ni)
                acc[mi][ni] = MFMA16(af[mi], bfv[ni], acc[mi][ni]);
    }

    const int bb = m0 >> 11;   // batch (tiles never straddle a batch)
    #pragma unroll
    for (int ni = 0; ni < 4; ++ni) {
        const int gc     = n0 + wn * 64 + ni * 16 + l15;
        const float bias = BIAS[gc];
        const int which  = gc >> 10;          // 0=q 1=k 2=v (uniform per block)
        const int rem    = gc & 1023;
        const int hh     = rem >> 6;
        const int dd     = rem & 63;
        #pragma unroll
        for (int mi = 0; mi < 4; ++mi) {
            const int nseq0 = (m0 & 2047) + wm * 64 + mi * 16 + quad * 4;
            floatx4 v = acc[mi][ni];
            if (which == 2) {
                ushort4 pk;
                pk.x = f2bf(v[0] + bias); pk.y = f2bf(v[1] + bias);
                pk.z = f2bf(v[2] + bias); pk.w = f2bf(v[3] + bias);
                *(ushort4*)&vtb[((size_t)(bb * NUM_HEADS + hh) * HEAD_DIM + dd) * SEQ + nseq0] = pk;
            } else {
                unsigned short* dst = which ? kb : qb;
                const float sc = which ? 1.0f : QSCALE;
                #pragma unroll
                for (int r = 0; r < 4; ++r)
                    dst[((size_t)(bb * NUM_HEADS + hh) * SEQ + (nseq0 + r)) * HEAD_DIM + dd] =
                        f2bf((v[r] + bias) * sc);
            }
        }
    }
}

// ---------------------------------------------------------------------------
// Kernel 2: flash attention on mfma_32x32x16, register-resident P, rot-swizzled
// K/V LDS tiles. Q staged through the K region pre-loop (frags are register-
// resident; loop's first barrier orders the overwrite). LDS 32 KB -> up to
// 5 blocks/CU. Fixed-max softmax; denominator via ones-MFMA; truncating pack.
// ---------------------------------------------------------------------------
__global__ __launch_bounds__(256, 4)
void attn_kernel(const unsigned short* __restrict__ qb, const unsigned short* __restrict__ kb,
                 const unsigned short* __restrict__ vtb, unsigned short* __restrict__ attnb)
{
    __shared__ unsigned short smem[16384];   // 32 KB

    const int t    = threadIdx.x;
    const int bh   = blockIdx.x;
    const int q0   = blockIdx.y * 128;
    const int b    = bh >> 4, hh = bh & 15;
    const int wave = t >> 6, lane = t & 63;
    const int l31  = lane & 31, hl = lane >> 5;
    const int srow = lane >> 2;              // 0..15
    const int scol = (lane & 3) * 8;                              // phys chunk
    const int gcol = (((lane & 3) - ((lane >> 3) & 3)) & 3) * 8;  // logical chunk
    const int rrot = (l31 >> 1) & 3;

    const unsigned short* qp = qb  + (size_t)bh * SEQ * HEAD_DIM;
    const unsigned short* kp = kb  + (size_t)bh * SEQ * HEAD_DIM;
    const unsigned short* vp = vtb + (size_t)bh * HEAD_DIM * SEQ;

    // ---- stage Q (async DMA) through the K region as two [128][32] halves ----
    {
        const int r0 = wave * 32 + srow;
        async16(qp + (size_t)(q0 + r0) * 64 + gcol,           &smem[r0 * 32 + scol]);
        async16(qp + (size_t)(q0 + r0 + 16) * 64 + gcol,      &smem[(r0 + 16) * 32 + scol]);
        async16(qp + (size_t)(q0 + r0) * 64 + 32 + gcol,      &smem[4096 + r0 * 32 + scol]);
        async16(qp + (size_t)(q0 + r0 + 16) * 64 + 32 + gcol, &smem[4096 + (r0 + 16) * 32 + scol]);
    }
    __syncthreads();
    // Q B-frags (32x32x16): n=q=wave*32+l31, k=d=ks*16+hl*8+j — loop-invariant
    bf16x8 qf[4];
    #pragma unroll
    for (int ks = 0; ks < 4; ++ks)
        qf[ks] = *(const bf16x8*)&smem[(ks >> 1) * 4096 +
                 (wave * 32 + l31) * 32 + ((((ks & 1) * 2 + hl) + rrot) & 3) * 8];

    bf16x8 ones;
    #pragma unroll
    for (int i = 0; i < 8; ++i) ones[i] = (__bf16)1.0f;

    floatx16 o[2], o_sum;
    #pragma unroll
    for (int i = 0; i < 16; ++i) { o[0][i] = 0.f; o[1][i] = 0.f; o_sum[i] = 0.f; }

    for (int kv0 = 0; kv0 < SEQ; kv0 += 128) {
        __syncthreads();   // prev iter's K/V reads (and the Q-frag reads) done
        {
            const int kr = wave * 32 + srow;
            async16(kp + (size_t)(kv0 + kr) * 64 + gcol,           &smem[kr * 32 + scol]);
            async16(kp + (size_t)(kv0 + kr + 16) * 64 + gcol,      &smem[(kr + 16) * 32 + scol]);
            async16(kp + (size_t)(kv0 + kr) * 64 + 32 + gcol,      &smem[4096 + kr * 32 + scol]);
            async16(kp + (size_t)(kv0 + kr + 16) * 64 + 32 + gcol, &smem[4096 + (kr + 16) * 32 + scol]);
            const int vd = wave * 16 + srow;   // 0..63
            #pragma unroll
            for (int kk = 0; kk < 4; ++kk)
                async16(vp + (size_t)vd * SEQ + kv0 + kk * 32 + gcol,
                        &smem[8192 + kk * 2048 + vd * 32 + scol]);
        }
        __syncthreads();

        #pragma unroll
        for (int tt = 0; tt < 4; ++tt) {        // 32-kv tiles
            // S^T tile: A=K (m=kv=tt*32+l31, k=d), B=Q
            floatx16 st;
            #pragma unroll
            for (int i = 0; i < 16; ++i) st[i] = 0.f;
            #pragma unroll
            for (int ks = 0; ks < 4; ++ks) {
                bf16x8 kf = *(const bf16x8*)&smem[(ks >> 1) * 4096 +
                            (tt * 32 + l31) * 32 + ((((ks & 1) * 2 + hl) + rrot) & 3) * 8];
                st = MFMA32(kf, qf[ks], st);
            }
            // exp2 + truncating pack: pk[g] holds kv {8g+4hl..8g+4hl+3}, q=l31
            uint2 pk0 = packbf4t(EXP2(st[0]),  EXP2(st[1]),  EXP2(st[2]),  EXP2(st[3]));
            uint2 pk1 = packbf4t(EXP2(st[4]),  EXP2(st[5]),  EXP2(st[6]),  EXP2(st[7]));
            uint2 pk2 = packbf4t(EXP2(st[8]),  EXP2(st[9]),  EXP2(st[10]), EXP2(st[11]));
            uint2 pk3 = packbf4t(EXP2(st[12]), EXP2(st[13]), EXP2(st[14]), EXP2(st[15]));

            // C->A layout fix: exchange across lane halves (shfl_xor 32)
            uint2 xa = hl ? pk0 : pk1;
            xa.x = __shfl_xor(xa.x, 32); xa.y = __shfl_xor(xa.y, 32);
            bf16x8 pfA = hl ? mk8(xa, pk1) : mk8(pk0, xa);   // kv blk tt*2+0
            uint2 xb2 = hl ? pk2 : pk3;
            xb2.x = __shfl_xor(xb2.x, 32); xb2.y = __shfl_xor(xb2.y, 32);
            bf16x8 pfB = hl ? mk8(xb2, pk3) : mk8(pk2, xb2); // kv blk tt*2+1

            // PV: O[q][d] += P @ V ; o_sum += P @ ones
            #pragma unroll
            for (int s = 0; s < 2; ++s) {
                const bf16x8 pf = s ? pfB : pfA;
                const int kvblk = tt * 2 + s;                // 16-kv block 0..7
                const int vbase = 8192 + (kvblk >> 1) * 2048;
                const int vchun = ((((kvblk & 1) * 2 + hl) + rrot) & 3) * 8;
                #pragma unroll
                for (int dt = 0; dt < 2; ++dt) {
                    bf16x8 vf = *(const bf16x8*)&smem[vbase + (dt * 32 + l31) * 32 + vchun];
                    o[dt] = MFMA32(pf, vf, o[dt]);
                }
                o_sum = MFMA32(pf, ones, o_sum);
            }
        }
    }

    // epilogue: O/l -> attn buffer [b, n, hh*64+d] bf16 (denominator in-lane:
    // o and o_sum share the C row mapping q=(e)+8g+4hl, col d=dt*32+l31)
    #pragma unroll
    for (int g = 0; g < 4; ++g)
        #pragma unroll
        for (int e = 0; e < 4; ++e) {
            const float inv  = 1.0f / o_sum[g * 4 + e];
            const int  qrow  = q0 + wave * 32 + e + g * 8 + hl * 4;
            #pragma unroll
            for (int dt = 0; dt < 2; ++dt)
                attnb[(size_t)(b * SEQ + qrow) * EMB + hh * HEAD_DIM + dt * 32 + l31] =
                    f2bf(o[dt][g * 4 + e] * inv);
        }
}

// ---------------------------------------------------------------------------
// Kernel 3: out = attn @ fc_w^T + fc_b  (all-bf16 m97-style GEMM, rot-swizzled
//           LDS, fp32 out)
// ---------------------------------------------------------------------------
__global__ __launch_bounds__(256, 3)
void proj_kernel(const unsigned short* __restrict__ A, const unsigned short* __restrict__ W,
                 const float* __restrict__ BIAS, float* __restrict__ out)
{
    __shared__ unsigned short As[128 * 32];
    __shared__ unsigned short Bs[128 * 32];

    const int t    = threadIdx.x;
    const int n0   = blockIdx.x * 128;
    const int m0   = blockIdx.y * 128;
    const int wave = t >> 6, lane = t & 63;
    const int wm   = wave & 1, wn = wave >> 1;
    const int l15  = lane & 15, quad = lane >> 4;

    const int srow = wave * 32 + (lane >> 2);
    const int scol = (lane & 3) * 8;
    const int gcol = (((lane & 3) - ((lane >> 3) & 3)) & 3) * 8;
    const unsigned short* gA = A + (size_t)(m0 + srow) * EMB + gcol;
    const unsigned short* gB = W + (size_t)(n0 + srow) * EMB + gcol;
    unsigned short* lA = &As[srow * 32 + scol];
    unsigned short* lB = &Bs[srow * 32 + scol];

    const int arot = (l15 >> 1) & 3;

    const floatx4 zero4 = {0.f, 0.f, 0.f, 0.f};
    floatx4 acc[4][4];
    #pragma unroll
    for (int i = 0; i < 4; ++i)
        #pragma unroll
        for (int j = 0; j < 4; ++j) acc[i][j] = zero4;

    for (int k0 = 0; k0 < EMB; k0 += 32) {
        __syncthreads();
        async16(gA + k0,                     lA);
        async16(gA + k0 + (size_t)16 * EMB,  lA + 16 * 32);
        async16(gB + k0,                     lB);
        async16(gB + k0 + (size_t)16 * EMB,  lB + 16 * 32);
        __syncthreads();

        bf16x8 af[4], bfv[4];
        #pragma unroll
        for (int i = 0; i < 4; ++i) {
            const int pc = ((quad + arot) & 3) * 8;
            af[i]  = *(const bf16x8*)&As[(wm * 64 + i * 16 + l15) * 32 + pc];
            bfv[i] = *(const bf16x8*)&Bs[(wn * 64 + i * 16 + l15) * 32 + pc];
        }
        #pragma unroll
        for (int mi = 0; mi < 4; ++mi)
            #pragma unroll
            for (int ni = 0; ni < 4; ++ni)
                acc[mi][ni] = MFMA16(af[mi], bfv[ni], acc[mi][ni]);
    }

    #pragma unroll
    for (int ni = 0; ni < 4; ++ni) {
        const int gc     = n0 + wn * 64 + ni * 16 + l15;
        const float bias = BIAS[gc];
        #pragma unroll
        for (int mi = 0; mi < 4; ++mi) {
            const int gm = m0 + wm * 64 + mi * 16 + quad * 4;
            #pragma unroll
            for (int r = 0; r < 4; ++r)
                out[(size_t)(gm + r) * EMB + gc] = acc[mi][ni][r] + bias;
        }
    }
}

// ---------------------------------------------------------------------------
extern "C" void kernel_launch(void* const* d_in, const int* in_sizes, int n_in,
                              void* d_out, int out_size, void* d_ws, size_t ws_size,
                              hipStream_t stream) {
    (void)in_sizes; (void)n_in; (void)out_size; (void)ws_size;
    const float* x     = (const float*)d_in[0];
    const float* qkv_w = (const float*)d_in[1];
    const float* qkv_b = (const float*)d_in[2];
    const float* fc_w  = (const float*)d_in[3];
    const float* fc_b  = (const float*)d_in[4];
    float* out = (float*)d_out;

    unsigned short* xb    = (unsigned short*)d_ws;        // 8.4M  (also attnb)
    unsigned short* attnb = xb;
    unsigned short* qbuf  = xb    + QKV_ELEMS;
    unsigned short* kbuf  = qbuf  + QKV_ELEMS;
    unsigned short* vtbuf = kbuf  + QKV_ELEMS;
    unsigned short* qwb   = vtbuf + QKV_ELEMS;            // 3.1M
    unsigned short* fwb   = qwb   + 3 * EMB * EMB;        // 1.0M

    convert_kernel<<<dim3((XV4 + QWV4 + FWV4) / 256), 256, 0, stream>>>(
        x, qkv_w, fc_w, xb, qwb, fwb);
    qkv_kernel<<<dim3(24, 64), 256, 0, stream>>>(xb, qwb, qkv_b, qbuf, kbuf, vtbuf);
    attn_kernel<<<dim3(64, 16), 256, 0, stream>>>(qbuf, kbuf, vtbuf, attnb);
    proj_kernel<<<dim3(8, 64), 256, 0, stream>>>(attnb, fwb, fc_b, out);
}